// Round 13
// baseline (151.918 us; speedup 1.0000x reference)
//
#include <hip/hip_runtime.h>
#include <hip/hip_bf16.h>
#include <math.h>

// MimiAttention: B=4, S=2048, HID=512, NH=8, HD=64, SW=250, theta=10000
// Round 13: revert to round-11 (best, 145.0us): BK=32, cvt-once bf16 staging,
// 4-slot XOR swizzle (2-way = free). BK=64 (round 12) regressed — barrier
// drains are already hidden by inter-block overlap; bigger staging bursts
// lengthen the serial bubble (matches m132). One tweak: n-dim on blockIdx.x
// in both GEMMs so blocks sharing an A m-tile dispatch temporally adjacent
// (L2 temporal locality).

#define B_   4
#define S_   2048
#define HID_ 512
#define NH_  8
#define HD_  64
#define SW_  250

typedef __bf16 bf16x8 __attribute__((ext_vector_type(8)));
typedef __bf16 bf16x4 __attribute__((ext_vector_type(4)));
typedef float f32x4 __attribute__((ext_vector_type(4)));
using bf16_t = __hip_bfloat16;
typedef unsigned int u32;

// async global->LDS, 16 B per lane (wave-uniform base + lane*16 semantics)
__device__ __forceinline__ void glds16(const void* g, void* l) {
    __builtin_amdgcn_global_load_lds(
        (const __attribute__((address_space(1))) u32*)g,
        (__attribute__((address_space(3))) u32*)l, 16, 0, 0);
}

// ---------------------------------------------------------------------------
// One fused fp32->bf16 convert pass. 2048 elems/block.
// blocks: [0,2048) X | [2048,2176) Wq | [2176,2304) Wk | [2304,2432) Wv |
//         [2432,2560) Wo
// ---------------------------------------------------------------------------
__global__ __launch_bounds__(256) void cvt_all(
    const float* __restrict__ X,  const float* __restrict__ Wq,
    const float* __restrict__ Wk, const float* __restrict__ Wv,
    const float* __restrict__ Wo,
    bf16_t* __restrict__ Xb, bf16_t* __restrict__ Wcat, bf16_t* __restrict__ Wob)
{
    const int blk = blockIdx.x;
    const float* s; bf16_t* d; size_t base;
    if (blk < 2048)      { s = X;  d = Xb;            base = (size_t)blk * 2048; }
    else if (blk < 2176) { s = Wq; d = Wcat;          base = (size_t)(blk - 2048) * 2048; }
    else if (blk < 2304) { s = Wk; d = Wcat + 262144; base = (size_t)(blk - 2176) * 2048; }
    else if (blk < 2432) { s = Wv; d = Wcat + 524288; base = (size_t)(blk - 2304) * 2048; }
    else                 { s = Wo; d = Wob;           base = (size_t)(blk - 2432) * 2048; }
    size_t i = base + (size_t)threadIdx.x * 8;
    float4 a = *reinterpret_cast<const float4*>(s + i);
    float4 b = *reinterpret_cast<const float4*>(s + i + 4);
    bf16x8 r;
    r[0] = (__bf16)a.x; r[1] = (__bf16)a.y; r[2] = (__bf16)a.z; r[3] = (__bf16)a.w;
    r[4] = (__bf16)b.x; r[5] = (__bf16)b.y; r[6] = (__bf16)b.z; r[7] = (__bf16)b.w;
    *reinterpret_cast<bf16x8*>(d + i) = r;
}

// ---------------------------------------------------------------------------
// Fused QKV GEMM: C[8192x1536] = Xb @ Wcat^T, 128x128 tile, BK=32, bf16
// staging with XOR-swizzled 16B slots (2-way bank access = free).
// grid (12 n-blocks, 64 m-blocks): n fastest for A-tile L2 temporal reuse.
// Epilogue: RoPE (__sincosf) for Q/K, V stored transposed; 128B-coalesced
// stores via wave-private LDS tile. MFMA layouts (m89/m91).
// ---------------------------------------------------------------------------
__global__ __launch_bounds__(256) void qkv_gemm(
    const bf16_t* __restrict__ Xb, const bf16_t* __restrict__ Wcat,
    bf16_t* __restrict__ Q, bf16_t* __restrict__ Kbuf, bf16_t* __restrict__ Vt)
{
    __shared__ __align__(16) char smem_raw[34816];  // max(16KB stage, 34KB epi)
    bf16_t* As = (bf16_t*)smem_raw;        // 128*32 bf16 = 8 KB
    bf16_t* Bs = As + 4096;                // 8 KB
    const int tid = threadIdx.x;
    const int wave = tid >> 6, lane = tid & 63;
    const int quad = lane >> 4, l16 = lane & 15;
    const int wm = wave & 1, wn = wave >> 1;
    const int m0 = blockIdx.y * 128, n0 = blockIdx.x * 128;   // n on x (fast)

    f32x4 acc[4][4] = {};
    for (int k0 = 0; k0 < HID_; k0 += 32) {
        // stage: 512 slots (16B) per tile, 2 rounds. physical slot rr*256+tid,
        // row = slot>>2, physical-in-row p = slot&3, logical l = p^((row>>1)&3)
#pragma unroll
        for (int rr = 0; rr < 2; ++rr) {
            int slot = rr * 256 + tid;
            int row = slot >> 2;
            int l = (slot & 3) ^ ((row >> 1) & 3);
            glds16(Xb + (size_t)(m0 + row) * HID_ + k0 + l * 8, As + slot * 8);
            glds16(Wcat + (size_t)(n0 + row) * HID_ + k0 + l * 8, Bs + slot * 8);
        }
        __syncthreads();
        bf16x8 af[4], bfr[4];
#pragma unroll
        for (int i = 0; i < 4; ++i) {
            int ra = wm * 64 + i * 16 + l16;
            int rb = wn * 64 + i * 16 + l16;
            int pa = quad ^ ((ra >> 1) & 3);
            int pb = quad ^ ((rb >> 1) & 3);
            af[i]  = *reinterpret_cast<const bf16x8*>(&As[ra * 32 + pa * 8]);
            bfr[i] = *reinterpret_cast<const bf16x8*>(&Bs[rb * 32 + pb * 8]);
        }
#pragma unroll
        for (int mi = 0; mi < 4; ++mi)
#pragma unroll
            for (int ni = 0; ni < 4; ++ni)
                acc[mi][ni] = __builtin_amdgcn_mfma_f32_16x16x32_bf16(af[mi], bfr[ni], acc[mi][ni], 0, 0, 0);
        __syncthreads();
    }

    // ---- epilogue via wave-private 64x68 bf16 LDS tile ----
    const int seg = n0 >> 9;                      // 0=Q 1=K 2=V
    const int hh = ((n0 & 511) + wn * 64) >> 6;   // head of this wave
    bf16_t* wt = (bf16_t*)smem_raw + wave * 4352;
    const int mbase = m0 + wm * 64;
    const int bb = mbase >> 11;
    const int sbase = mbase & (S_ - 1);           // 64-row tile never crosses batch

    if (seg < 2) {
        const float qs = (seg == 0) ? 0.125f : 1.0f;
        const float c = 0.41524101186f;           // log2(10000)/32
        float inv0 = exp2f(-(float)l16 * c);
        float inv1 = exp2f(-(float)(l16 + 16) * c);
#pragma unroll
        for (int mi = 0; mi < 4; ++mi)
#pragma unroll
            for (int r = 0; r < 4; ++r) {
                int lrow = mi * 16 + quad * 4 + r;
                float sf = (float)(sbase + lrow);
#pragma unroll
                for (int ip = 0; ip < 2; ++ip) {
                    float sn, cs_;
                    __sincosf(sf * (ip ? inv1 : inv0), &sn, &cs_);
                    float x1 = acc[mi][ip][r], x2 = acc[mi][ip + 2][r];
                    wt[lrow * 68 + ip * 16 + l16]      = __float2bfloat16((x1 * cs_ - x2 * sn) * qs);
                    wt[lrow * 68 + ip * 16 + l16 + 32] = __float2bfloat16((x2 * cs_ + x1 * sn) * qs);
                }
            }
        bf16_t* Y = (seg == 0) ? Q : Kbuf;
#pragma unroll
        for (int it = 0; it < 8; ++it) {
            int e = it * 64 + lane;
            int sr = e >> 3, doff = (e & 7) * 8;
            size_t g = ((size_t)(bb * NH_ + hh) * S_ + sbase + sr) * HD_ + doff;
            *reinterpret_cast<bf16x8*>(Y + g) =
                *reinterpret_cast<const bf16x8*>(wt + sr * 68 + doff);
        }
    } else {
        // V: deposit transposed (rows = d, cols = s-local), store along s
#pragma unroll
        for (int mi = 0; mi < 4; ++mi)
#pragma unroll
            for (int ni = 0; ni < 4; ++ni)
#pragma unroll
                for (int r = 0; r < 4; ++r)
                    wt[(ni * 16 + l16) * 68 + mi * 16 + quad * 4 + r] =
                        __float2bfloat16(acc[mi][ni][r]);
#pragma unroll
        for (int it = 0; it < 8; ++it) {
            int e = it * 64 + lane;
            int d = e >> 3, soff = (e & 7) * 8;
            size_t g = ((size_t)(bb * NH_ + hh) * HD_ + d) * S_ + sbase + soff;
            *reinterpret_cast<bf16x8*>(Vt + g) =
                *reinterpret_cast<const bf16x8*>(wt + d * 68 + soff);
        }
    }
}

// ---------------------------------------------------------------------------
// One-pass full-window attention (unchanged; passed rounds 6/8/9/10/11/12).
// ---------------------------------------------------------------------------
__global__ __launch_bounds__(256) void attn_mfma(
    const bf16_t* __restrict__ Q, const bf16_t* __restrict__ K,
    const bf16_t* __restrict__ Vt, bf16_t* __restrict__ A)
{
    __shared__ __align__(16) __bf16 pt[4][16][296];
    __shared__ float sums_l[4][16];
    const int wave = threadIdx.x >> 6, lane = threadIdx.x & 63;
    const int quad = lane >> 4, l16 = lane & 15;
    const int h = blockIdx.y, b = blockIdx.z;
    const int q0 = (blockIdx.x * 4 + wave) * 16;
    const size_t bh  = (size_t)(b * NH_ + h) * S_;
    const size_t bhd = (size_t)(b * NH_ + h) * HD_;

    bf16x8 qf0, qf1;
    {
        const bf16_t* qp = Q + (bh + q0 + l16) * HD_ + quad * 8;
        qf0 = *reinterpret_cast<const bf16x8*>(qp);
        qf1 = *reinterpret_cast<const bf16x8*>(qp + 32);
    }
    const int kstart = (q0 > SW_) ? ((q0 - SW_) & ~31) : 0;
    const int nt = (q0 + 15 - kstart + 32) >> 5;   // 1..9, wave-uniform
    const int qq = q0 + l16;

    f32x4 s[9][2];
#pragma unroll
    for (int t = 0; t < 9; ++t) {
        if (t < nt) {
            const int kb = kstart + t * 32;
#pragma unroll
            for (int half = 0; half < 2; ++half) {
                const bf16_t* kp = K + (bh + kb + half * 16 + l16) * HD_ + quad * 8;
                bf16x8 k0 = *reinterpret_cast<const bf16x8*>(kp);
                bf16x8 k1 = *reinterpret_cast<const bf16x8*>(kp + 32);
                f32x4 z = {};
                z = __builtin_amdgcn_mfma_f32_16x16x32_bf16(k0, qf0, z, 0, 0, 0);
                z = __builtin_amdgcn_mfma_f32_16x16x32_bf16(k1, qf1, z, 0, 0, 0);
                const int kbase = kb + half * 16 + quad * 4;
#pragma unroll
                for (int r = 0; r < 4; ++r) {
                    int key = kbase + r;
                    bool keep = (key <= qq) && (qq - key <= SW_);
                    s[t][half][r] = keep ? z[r] : -3.0e38f;
                }
            }
        }
    }
    float mx = -3.0e38f;
#pragma unroll
    for (int t = 0; t < 9; ++t)
        if (t < nt)
#pragma unroll
            for (int half = 0; half < 2; ++half)
#pragma unroll
                for (int r = 0; r < 4; ++r)
                    mx = fmaxf(mx, s[t][half][r]);
    mx = fmaxf(mx, __shfl_xor(mx, 16, 64));
    mx = fmaxf(mx, __shfl_xor(mx, 32, 64));

    float sum = 0.f;
#pragma unroll
    for (int t = 0; t < 9; ++t)
        if (t < nt)
#pragma unroll
            for (int half = 0; half < 2; ++half) {
                bf16x4 pk;
#pragma unroll
                for (int r = 0; r < 4; ++r) {
                    float p = __expf(s[t][half][r] - mx);
                    sum += p;
                    pk[r] = (__bf16)p;
                }
                *reinterpret_cast<bf16x4*>(&pt[wave][l16][t * 32 + half * 16 + quad * 4]) = pk;
            }
    sum += __shfl_xor(sum, 16, 64);
    sum += __shfl_xor(sum, 32, 64);
    if (quad == 0) sums_l[wave][l16] = sum;   // wave-local, no barrier

    f32x4 o[4] = {};
#pragma unroll
    for (int t = 0; t < 9; ++t) {
        if (t < nt) {
            const int kb = kstart + t * 32;
            bf16x8 pf = *reinterpret_cast<const bf16x8*>(&pt[wave][l16][t * 32 + quad * 8]);
#pragma unroll
            for (int nf = 0; nf < 4; ++nf) {
                const bf16_t* vp = Vt + (bhd + nf * 16 + l16) * S_ + kb + quad * 8;
                bf16x8 vf = *reinterpret_cast<const bf16x8*>(vp);
                o[nf] = __builtin_amdgcn_mfma_f32_16x16x32_bf16(pf, vf, o[nf], 0, 0, 0);
            }
        }
    }
    float inv_l[4];
#pragma unroll
    for (int r = 0; r < 4; ++r) inv_l[r] = 1.0f / sums_l[wave][quad * 4 + r];
#pragma unroll
    for (int nf = 0; nf < 4; ++nf)
#pragma unroll
        for (int r = 0; r < 4; ++r) {
            int qr = q0 + quad * 4 + r;
            A[((size_t)(b * S_ + qr)) * HID_ + h * HD_ + nf * 16 + l16] =
                __float2bfloat16(o[nf][r] * inv_l[r]);
        }
}

// ---------------------------------------------------------------------------
// Output projection: out[8192x512] = A @ Wob^T (both bf16), 128x64 tile,
// BK=32, swizzled staging, fp32 out. grid (8 n, 64 m): n fastest.
// ---------------------------------------------------------------------------
__global__ __launch_bounds__(256) void out_proj(
    const bf16_t* __restrict__ Ain, const bf16_t* __restrict__ Wob,
    float* __restrict__ out)
{
    __shared__ __align__(16) bf16_t As[128 * 32];  // 8 KB
    __shared__ __align__(16) bf16_t Bs[64 * 32];   // 4 KB
    const int tid = threadIdx.x;
    const int wave = tid >> 6, lane = tid & 63;
    const int quad = lane >> 4, l16 = lane & 15;
    const int m0 = blockIdx.y * 128, n0 = blockIdx.x * 64;   // n on x (fast)

    f32x4 acc[2][4] = {};
    for (int k0 = 0; k0 < HID_; k0 += 32) {
#pragma unroll
        for (int rr = 0; rr < 2; ++rr) {
            int slot = rr * 256 + tid;
            int row = slot >> 2;
            int l = (slot & 3) ^ ((row >> 1) & 3);
            glds16(Ain + (size_t)(m0 + row) * HID_ + k0 + l * 8, As + slot * 8);
        }
        {
            int slot = tid;                        // 256 slots: one round
            int row = slot >> 2;
            int l = (slot & 3) ^ ((row >> 1) & 3);
            glds16(Wob + (size_t)(n0 + row) * HID_ + k0 + l * 8, Bs + slot * 8);
        }
        __syncthreads();
        bf16x8 af[2], bfr[4];
#pragma unroll
        for (int i = 0; i < 2; ++i) {
            int ra = wave * 32 + i * 16 + l16;
            int pa = quad ^ ((ra >> 1) & 3);
            af[i] = *reinterpret_cast<const bf16x8*>(&As[ra * 32 + pa * 8]);
        }
#pragma unroll
        for (int i = 0; i < 4; ++i) {
            int rb = i * 16 + l16;
            int pb = quad ^ ((rb >> 1) & 3);
            bfr[i] = *reinterpret_cast<const bf16x8*>(&Bs[rb * 32 + pb * 8]);
        }
#pragma unroll
        for (int mi = 0; mi < 2; ++mi)
#pragma unroll
            for (int ni = 0; ni < 4; ++ni)
                acc[mi][ni] = __builtin_amdgcn_mfma_f32_16x16x32_bf16(af[mi], bfr[ni], acc[mi][ni], 0, 0, 0);
        __syncthreads();
    }
#pragma unroll
    for (int mi = 0; mi < 2; ++mi)
#pragma unroll
        for (int ni = 0; ni < 4; ++ni)
#pragma unroll
            for (int r = 0; r < 4; ++r) {
                int m = m0 + wave * 32 + mi * 16 + quad * 4 + r;
                int n = n0 + ni * 16 + l16;
                out[(size_t)m * HID_ + n] = acc[mi][ni][r];
            }
}

// ---------------------------------------------------------------------------
extern "C" void kernel_launch(void* const* d_in, const int* in_sizes, int n_in,
                              void* d_out, int out_size, void* d_ws, size_t ws_size,
                              hipStream_t stream)
{
    const float* X  = (const float*)d_in[0];
    // d_in[1] = position_ids (broadcast arange(S); pos derived from s index)
    const float* Wq = (const float*)d_in[2];
    const float* Wk = (const float*)d_in[3];
    const float* Wv = (const float*)d_in[4];
    const float* Wo = (const float*)d_in[5];

    char* ws = (char*)d_ws;
    const size_t elems = (size_t)B_ * NH_ * S_ * HD_;   // 4,194,304
    const size_t wsz   = (size_t)HID_ * HID_;           // 262,144
    bf16_t* Q    = (bf16_t*)ws;
    bf16_t* K    = Q + elems;
    bf16_t* Vt   = K + elems;
    bf16_t* Xb   = Vt + elems;          // aliased: A overwrites Xb after qkv
    bf16_t* A    = Xb;
    bf16_t* Wcat = Xb + elems;
    bf16_t* Wob  = Wcat + 3 * wsz;      // total ~35.6 MB

    cvt_all<<<2560, 256, 0, stream>>>(X, Wq, Wk, Wv, Wo, Xb, Wcat, Wob);
    qkv_gemm<<<dim3(12, 64), 256, 0, stream>>>(Xb, Wcat, Q, K, Vt);
    attn_mfma<<<dim3(32, 8, 4), 256, 0, stream>>>(Q, K, Vt, A);
    out_proj<<<dim3(8, 64), 256, 0, stream>>>(A, Wob, (float*)d_out);
}

// Round 14
// 145.821 us; speedup vs baseline: 1.0418x; 1.0418x over previous
//
#include <hip/hip_runtime.h>
#include <hip/hip_bf16.h>
#include <math.h>

// MimiAttention: B=4, S=2048, HID=512, NH=8, HD=64, SW=250, theta=10000
// Round 14 = exact round-11 revert (session best, 145.0us). BK=32, cvt-once
// bf16 staging, 4-slot XOR swizzle (2-way LDS = free), m-fast grids.
// Probes off this optimum both regressed: BK=64 (r12, +5us: staging burst
// outweighs barrier savings, cf. m132) and n-fast grid (r13, +7us: adjacent
// ids land on different XCDs, destroying same-XCD B-tile L2 sharing).
// Kernels: cvt_all -> qkv_gemm(+RoPE,Vt) -> attn_mfma -> out_proj.

#define B_   4
#define S_   2048
#define HID_ 512
#define NH_  8
#define HD_  64
#define SW_  250

typedef __bf16 bf16x8 __attribute__((ext_vector_type(8)));
typedef __bf16 bf16x4 __attribute__((ext_vector_type(4)));
typedef float f32x4 __attribute__((ext_vector_type(4)));
using bf16_t = __hip_bfloat16;
typedef unsigned int u32;

// async global->LDS, 16 B per lane (wave-uniform base + lane*16 semantics)
__device__ __forceinline__ void glds16(const void* g, void* l) {
    __builtin_amdgcn_global_load_lds(
        (const __attribute__((address_space(1))) u32*)g,
        (__attribute__((address_space(3))) u32*)l, 16, 0, 0);
}

// ---------------------------------------------------------------------------
// One fused fp32->bf16 convert pass. 2048 elems/block.
// blocks: [0,2048) X | [2048,2176) Wq | [2176,2304) Wk | [2304,2432) Wv |
//         [2432,2560) Wo
// ---------------------------------------------------------------------------
__global__ __launch_bounds__(256) void cvt_all(
    const float* __restrict__ X,  const float* __restrict__ Wq,
    const float* __restrict__ Wk, const float* __restrict__ Wv,
    const float* __restrict__ Wo,
    bf16_t* __restrict__ Xb, bf16_t* __restrict__ Wcat, bf16_t* __restrict__ Wob)
{
    const int blk = blockIdx.x;
    const float* s; bf16_t* d; size_t base;
    if (blk < 2048)      { s = X;  d = Xb;            base = (size_t)blk * 2048; }
    else if (blk < 2176) { s = Wq; d = Wcat;          base = (size_t)(blk - 2048) * 2048; }
    else if (blk < 2304) { s = Wk; d = Wcat + 262144; base = (size_t)(blk - 2176) * 2048; }
    else if (blk < 2432) { s = Wv; d = Wcat + 524288; base = (size_t)(blk - 2304) * 2048; }
    else                 { s = Wo; d = Wob;           base = (size_t)(blk - 2432) * 2048; }
    size_t i = base + (size_t)threadIdx.x * 8;
    float4 a = *reinterpret_cast<const float4*>(s + i);
    float4 b = *reinterpret_cast<const float4*>(s + i + 4);
    bf16x8 r;
    r[0] = (__bf16)a.x; r[1] = (__bf16)a.y; r[2] = (__bf16)a.z; r[3] = (__bf16)a.w;
    r[4] = (__bf16)b.x; r[5] = (__bf16)b.y; r[6] = (__bf16)b.z; r[7] = (__bf16)b.w;
    *reinterpret_cast<bf16x8*>(d + i) = r;
}

// ---------------------------------------------------------------------------
// Fused QKV GEMM: C[8192x1536] = Xb @ Wcat^T, 128x128 tile, BK=32, bf16
// staging with XOR-swizzled 16B slots (2-way bank access = free).
// Epilogue: RoPE (__sincosf) for Q/K, V stored transposed; 128B-coalesced
// stores via wave-private LDS tile. MFMA layouts (m89/m91).
// ---------------------------------------------------------------------------
__global__ __launch_bounds__(256) void qkv_gemm(
    const bf16_t* __restrict__ Xb, const bf16_t* __restrict__ Wcat,
    bf16_t* __restrict__ Q, bf16_t* __restrict__ Kbuf, bf16_t* __restrict__ Vt)
{
    __shared__ __align__(16) char smem_raw[34816];  // max(16KB stage, 34KB epi)
    bf16_t* As = (bf16_t*)smem_raw;        // 128*32 bf16 = 8 KB
    bf16_t* Bs = As + 4096;                // 8 KB
    const int tid = threadIdx.x;
    const int wave = tid >> 6, lane = tid & 63;
    const int quad = lane >> 4, l16 = lane & 15;
    const int wm = wave & 1, wn = wave >> 1;
    const int m0 = blockIdx.x * 128, n0 = blockIdx.y * 128;

    f32x4 acc[4][4] = {};
    for (int k0 = 0; k0 < HID_; k0 += 32) {
        // stage: 512 slots (16B) per tile, 2 rounds. physical slot rr*256+tid,
        // row = slot>>2, physical-in-row p = slot&3, logical l = p^((row>>1)&3)
#pragma unroll
        for (int rr = 0; rr < 2; ++rr) {
            int slot = rr * 256 + tid;
            int row = slot >> 2;
            int l = (slot & 3) ^ ((row >> 1) & 3);
            glds16(Xb + (size_t)(m0 + row) * HID_ + k0 + l * 8, As + slot * 8);
            glds16(Wcat + (size_t)(n0 + row) * HID_ + k0 + l * 8, Bs + slot * 8);
        }
        __syncthreads();
        bf16x8 af[4], bfr[4];
#pragma unroll
        for (int i = 0; i < 4; ++i) {
            int ra = wm * 64 + i * 16 + l16;
            int rb = wn * 64 + i * 16 + l16;
            int pa = quad ^ ((ra >> 1) & 3);
            int pb = quad ^ ((rb >> 1) & 3);
            af[i]  = *reinterpret_cast<const bf16x8*>(&As[ra * 32 + pa * 8]);
            bfr[i] = *reinterpret_cast<const bf16x8*>(&Bs[rb * 32 + pb * 8]);
        }
#pragma unroll
        for (int mi = 0; mi < 4; ++mi)
#pragma unroll
            for (int ni = 0; ni < 4; ++ni)
                acc[mi][ni] = __builtin_amdgcn_mfma_f32_16x16x32_bf16(af[mi], bfr[ni], acc[mi][ni], 0, 0, 0);
        __syncthreads();
    }

    // ---- epilogue via wave-private 64x68 bf16 LDS tile ----
    const int seg = n0 >> 9;                      // 0=Q 1=K 2=V
    const int hh = ((n0 & 511) + wn * 64) >> 6;   // head of this wave
    bf16_t* wt = (bf16_t*)smem_raw + wave * 4352;
    const int mbase = m0 + wm * 64;
    const int bb = mbase >> 11;
    const int sbase = mbase & (S_ - 1);           // 64-row tile never crosses batch

    if (seg < 2) {
        const float qs = (seg == 0) ? 0.125f : 1.0f;
        const float c = 0.41524101186f;           // log2(10000)/32
        float inv0 = exp2f(-(float)l16 * c);
        float inv1 = exp2f(-(float)(l16 + 16) * c);
#pragma unroll
        for (int mi = 0; mi < 4; ++mi)
#pragma unroll
            for (int r = 0; r < 4; ++r) {
                int lrow = mi * 16 + quad * 4 + r;
                float sf = (float)(sbase + lrow);
#pragma unroll
                for (int ip = 0; ip < 2; ++ip) {
                    float sn, cs_;
                    __sincosf(sf * (ip ? inv1 : inv0), &sn, &cs_);
                    float x1 = acc[mi][ip][r], x2 = acc[mi][ip + 2][r];
                    wt[lrow * 68 + ip * 16 + l16]      = __float2bfloat16((x1 * cs_ - x2 * sn) * qs);
                    wt[lrow * 68 + ip * 16 + l16 + 32] = __float2bfloat16((x2 * cs_ + x1 * sn) * qs);
                }
            }
        bf16_t* Y = (seg == 0) ? Q : Kbuf;
#pragma unroll
        for (int it = 0; it < 8; ++it) {
            int e = it * 64 + lane;
            int sr = e >> 3, doff = (e & 7) * 8;
            size_t g = ((size_t)(bb * NH_ + hh) * S_ + sbase + sr) * HD_ + doff;
            *reinterpret_cast<bf16x8*>(Y + g) =
                *reinterpret_cast<const bf16x8*>(wt + sr * 68 + doff);
        }
    } else {
        // V: deposit transposed (rows = d, cols = s-local), store along s
#pragma unroll
        for (int mi = 0; mi < 4; ++mi)
#pragma unroll
            for (int ni = 0; ni < 4; ++ni)
#pragma unroll
                for (int r = 0; r < 4; ++r)
                    wt[(ni * 16 + l16) * 68 + mi * 16 + quad * 4 + r] =
                        __float2bfloat16(acc[mi][ni][r]);
#pragma unroll
        for (int it = 0; it < 8; ++it) {
            int e = it * 64 + lane;
            int d = e >> 3, soff = (e & 7) * 8;
            size_t g = ((size_t)(bb * NH_ + hh) * HD_ + d) * S_ + sbase + soff;
            *reinterpret_cast<bf16x8*>(Vt + g) =
                *reinterpret_cast<const bf16x8*>(wt + d * 68 + soff);
        }
    }
}

// ---------------------------------------------------------------------------
// One-pass full-window attention (unchanged; passed rounds 6/8/9/10/11/12/13).
// ---------------------------------------------------------------------------
__global__ __launch_bounds__(256) void attn_mfma(
    const bf16_t* __restrict__ Q, const bf16_t* __restrict__ K,
    const bf16_t* __restrict__ Vt, bf16_t* __restrict__ A)
{
    __shared__ __align__(16) __bf16 pt[4][16][296];
    __shared__ float sums_l[4][16];
    const int wave = threadIdx.x >> 6, lane = threadIdx.x & 63;
    const int quad = lane >> 4, l16 = lane & 15;
    const int h = blockIdx.y, b = blockIdx.z;
    const int q0 = (blockIdx.x * 4 + wave) * 16;
    const size_t bh  = (size_t)(b * NH_ + h) * S_;
    const size_t bhd = (size_t)(b * NH_ + h) * HD_;

    bf16x8 qf0, qf1;
    {
        const bf16_t* qp = Q + (bh + q0 + l16) * HD_ + quad * 8;
        qf0 = *reinterpret_cast<const bf16x8*>(qp);
        qf1 = *reinterpret_cast<const bf16x8*>(qp + 32);
    }
    const int kstart = (q0 > SW_) ? ((q0 - SW_) & ~31) : 0;
    const int nt = (q0 + 15 - kstart + 32) >> 5;   // 1..9, wave-uniform
    const int qq = q0 + l16;

    f32x4 s[9][2];
#pragma unroll
    for (int t = 0; t < 9; ++t) {
        if (t < nt) {
            const int kb = kstart + t * 32;
#pragma unroll
            for (int half = 0; half < 2; ++half) {
                const bf16_t* kp = K + (bh + kb + half * 16 + l16) * HD_ + quad * 8;
                bf16x8 k0 = *reinterpret_cast<const bf16x8*>(kp);
                bf16x8 k1 = *reinterpret_cast<const bf16x8*>(kp + 32);
                f32x4 z = {};
                z = __builtin_amdgcn_mfma_f32_16x16x32_bf16(k0, qf0, z, 0, 0, 0);
                z = __builtin_amdgcn_mfma_f32_16x16x32_bf16(k1, qf1, z, 0, 0, 0);
                const int kbase = kb + half * 16 + quad * 4;
#pragma unroll
                for (int r = 0; r < 4; ++r) {
                    int key = kbase + r;
                    bool keep = (key <= qq) && (qq - key <= SW_);
                    s[t][half][r] = keep ? z[r] : -3.0e38f;
                }
            }
        }
    }
    float mx = -3.0e38f;
#pragma unroll
    for (int t = 0; t < 9; ++t)
        if (t < nt)
#pragma unroll
            for (int half = 0; half < 2; ++half)
#pragma unroll
                for (int r = 0; r < 4; ++r)
                    mx = fmaxf(mx, s[t][half][r]);
    mx = fmaxf(mx, __shfl_xor(mx, 16, 64));
    mx = fmaxf(mx, __shfl_xor(mx, 32, 64));

    float sum = 0.f;
#pragma unroll
    for (int t = 0; t < 9; ++t)
        if (t < nt)
#pragma unroll
            for (int half = 0; half < 2; ++half) {
                bf16x4 pk;
#pragma unroll
                for (int r = 0; r < 4; ++r) {
                    float p = __expf(s[t][half][r] - mx);
                    sum += p;
                    pk[r] = (__bf16)p;
                }
                *reinterpret_cast<bf16x4*>(&pt[wave][l16][t * 32 + half * 16 + quad * 4]) = pk;
            }
    sum += __shfl_xor(sum, 16, 64);
    sum += __shfl_xor(sum, 32, 64);
    if (quad == 0) sums_l[wave][l16] = sum;   // wave-local, no barrier

    f32x4 o[4] = {};
#pragma unroll
    for (int t = 0; t < 9; ++t) {
        if (t < nt) {
            const int kb = kstart + t * 32;
            bf16x8 pf = *reinterpret_cast<const bf16x8*>(&pt[wave][l16][t * 32 + quad * 8]);
#pragma unroll
            for (int nf = 0; nf < 4; ++nf) {
                const bf16_t* vp = Vt + (bhd + nf * 16 + l16) * S_ + kb + quad * 8;
                bf16x8 vf = *reinterpret_cast<const bf16x8*>(vp);
                o[nf] = __builtin_amdgcn_mfma_f32_16x16x32_bf16(pf, vf, o[nf], 0, 0, 0);
            }
        }
    }
    float inv_l[4];
#pragma unroll
    for (int r = 0; r < 4; ++r) inv_l[r] = 1.0f / sums_l[wave][quad * 4 + r];
#pragma unroll
    for (int nf = 0; nf < 4; ++nf)
#pragma unroll
        for (int r = 0; r < 4; ++r) {
            int qr = q0 + quad * 4 + r;
            A[((size_t)(b * S_ + qr)) * HID_ + h * HD_ + nf * 16 + l16] =
                __float2bfloat16(o[nf][r] * inv_l[r]);
        }
}

// ---------------------------------------------------------------------------
// Output projection: out[8192x512] = A @ Wob^T (both bf16), 128x64 tile,
// BK=32, swizzled staging, fp32 out.
// ---------------------------------------------------------------------------
__global__ __launch_bounds__(256) void out_proj(
    const bf16_t* __restrict__ Ain, const bf16_t* __restrict__ Wob,
    float* __restrict__ out)
{
    __shared__ __align__(16) bf16_t As[128 * 32];  // 8 KB
    __shared__ __align__(16) bf16_t Bs[64 * 32];   // 4 KB
    const int tid = threadIdx.x;
    const int wave = tid >> 6, lane = tid & 63;
    const int quad = lane >> 4, l16 = lane & 15;
    const int m0 = blockIdx.x * 128, n0 = blockIdx.y * 64;

    f32x4 acc[2][4] = {};
    for (int k0 = 0; k0 < HID_; k0 += 32) {
#pragma unroll
        for (int rr = 0; rr < 2; ++rr) {
            int slot = rr * 256 + tid;
            int row = slot >> 2;
            int l = (slot & 3) ^ ((row >> 1) & 3);
            glds16(Ain + (size_t)(m0 + row) * HID_ + k0 + l * 8, As + slot * 8);
        }
        {
            int slot = tid;                        // 256 slots: one round
            int row = slot >> 2;
            int l = (slot & 3) ^ ((row >> 1) & 3);
            glds16(Wob + (size_t)(n0 + row) * HID_ + k0 + l * 8, Bs + slot * 8);
        }
        __syncthreads();
        bf16x8 af[2], bfr[4];
#pragma unroll
        for (int i = 0; i < 2; ++i) {
            int ra = wave * 32 + i * 16 + l16;
            int pa = quad ^ ((ra >> 1) & 3);
            af[i] = *reinterpret_cast<const bf16x8*>(&As[ra * 32 + pa * 8]);
        }
#pragma unroll
        for (int i = 0; i < 4; ++i) {
            int rb = i * 16 + l16;
            int pb = quad ^ ((rb >> 1) & 3);
            bfr[i] = *reinterpret_cast<const bf16x8*>(&Bs[rb * 32 + pb * 8]);
        }
#pragma unroll
        for (int mi = 0; mi < 2; ++mi)
#pragma unroll
            for (int ni = 0; ni < 4; ++ni)
                acc[mi][ni] = __builtin_amdgcn_mfma_f32_16x16x32_bf16(af[mi], bfr[ni], acc[mi][ni], 0, 0, 0);
        __syncthreads();
    }
#pragma unroll
    for (int mi = 0; mi < 2; ++mi)
#pragma unroll
        for (int ni = 0; ni < 4; ++ni)
#pragma unroll
            for (int r = 0; r < 4; ++r) {
                int m = m0 + wave * 32 + mi * 16 + quad * 4 + r;
                int n = n0 + ni * 16 + l16;
                out[(size_t)m * HID_ + n] = acc[mi][ni][r];
            }
}

// ---------------------------------------------------------------------------
extern "C" void kernel_launch(void* const* d_in, const int* in_sizes, int n_in,
                              void* d_out, int out_size, void* d_ws, size_t ws_size,
                              hipStream_t stream)
{
    const float* X  = (const float*)d_in[0];
    // d_in[1] = position_ids (broadcast arange(S); pos derived from s index)
    const float* Wq = (const float*)d_in[2];
    const float* Wk = (const float*)d_in[3];
    const float* Wv = (const float*)d_in[4];
    const float* Wo = (const float*)d_in[5];

    char* ws = (char*)d_ws;
    const size_t elems = (size_t)B_ * NH_ * S_ * HD_;   // 4,194,304
    const size_t wsz   = (size_t)HID_ * HID_;           // 262,144
    bf16_t* Q    = (bf16_t*)ws;
    bf16_t* K    = Q + elems;
    bf16_t* Vt   = K + elems;
    bf16_t* Xb   = Vt + elems;          // aliased: A overwrites Xb after qkv
    bf16_t* A    = Xb;
    bf16_t* Wcat = Xb + elems;
    bf16_t* Wob  = Wcat + 3 * wsz;      // total ~35.6 MB

    cvt_all<<<2560, 256, 0, stream>>>(X, Wq, Wk, Wv, Wo, Xb, Wcat, Wob);
    qkv_gemm<<<dim3(64, 12), 256, 0, stream>>>(Xb, Wcat, Q, K, Vt);
    attn_mfma<<<dim3(32, 8, 4), 256, 0, stream>>>(Q, K, Vt, A);
    out_proj<<<dim3(64, 8), 256, 0, stream>>>(A, Wob, (float*)d_out);
}